// Round 1
// 60.982 us; speedup vs baseline: 1.0326x; 1.0326x over previous
//
#include <hip/hip_runtime.h>

// 6-qubit circuit, ONE sample per lane, full state (64 amps) in registers.
//
// Amp index i (6 bits, qubit w <-> bit (5-w)):
//   b5=q0 b4=q1 b3=q2 b2=q3 b1=q4 b0=q5   (PennyLane wire order, C-order flatten)
// Each amp is v2f {re, im}. RX encoding gives amp = (-i)^popc(q0..q3 bits) * real;
// all later gates (RY/CNOT) are real, so re/im evolve identically -> v_pk_fma_f32.
// B = 65536 -> 1024 waves = exactly 1 wave/SIMD on MI355X: register pressure is
// free (no occupancy to lose), so all CNOTs are compile-time register renames
// and there is zero cross-lane traffic.

#define NL 2

typedef float v2f __attribute__((ext_vector_type(2)));

__global__ __launch_bounds__(256, 1) void qcirc6_reg_kernel(
    const float* __restrict__ x,        // (B, 4)
    const float* __restrict__ weights,  // (NL, 6)
    const float* __restrict__ bias,     // (2,)
    float* __restrict__ out,            // (B, 4)
    int B)
{
    const int sample = blockIdx.x * blockDim.x + threadIdx.x;
    if (sample >= B) return;

    // ---- encoding angles: one coalesced float4 per lane ----
    const float4 xv = *reinterpret_cast<const float4*>(x + sample * 4);
    float s0, c0, s1, c1, s2, c2, s3, c3;
    __sincosf(xv.x * 0.5f, &s0, &c0);
    __sincosf(xv.y * 0.5f, &s1, &c1);
    __sincosf(xv.z * 0.5f, &s2, &c2);
    __sincosf(xv.w * 0.5f, &s3, &c3);
    float sb0, cb0, sb1, cb1;
    __sincosf(bias[0] * 0.5f, &sb0, &cb0);
    __sincosf(bias[1] * 0.5f, &sb1, &cb1);

    // ---- product-state init ----
    // v0123[h] over q0..q3 (h bit3=q0 .. bit0=q3), v45[l] over ancillas (l bit1=q4, bit0=q5)
    const float v01[4] = {c0 * c1, c0 * s1, s0 * c1, s0 * s1};
    const float v23[4] = {c2 * c3, c2 * s3, s2 * c3, s2 * s3};
    const float v45[4] = {cb0 * cb1, cb0 * sb1, sb0 * cb1, sb0 * sb1};

    v2f a[64];
    #pragma unroll
    for (int h = 0; h < 16; ++h) {
        const int m = ((h & 1) + ((h >> 1) & 1) + ((h >> 2) & 1) + ((h >> 3) & 1)) & 3;
        const float vh = v01[h >> 2] * v23[h & 3];
        #pragma unroll
        for (int l = 0; l < 4; ++l) {
            const float val = vh * v45[l];
            v2f av;
            if      (m == 0) { av.x =  val; av.y = 0.f;  }
            else if (m == 1) { av.x = 0.f;  av.y = -val; }
            else if (m == 2) { av.x = -val; av.y = 0.f;  }
            else             { av.x = 0.f;  av.y =  val; }
            a[(h << 2) | l] = av;
        }
    }

    // CNOT(c,t): for amps with control bit set, flip target bit -> pure register rename
    #define CNOT(CM, TM)                                              \
        _Pragma("unroll")                                             \
        for (int i = 0; i < 64; ++i) {                                \
            if ((i & (CM)) && !(i & (TM))) {                          \
                const int j = i | (TM);                               \
                const v2f tmp = a[i]; a[i] = a[j]; a[j] = tmp;        \
            }                                                         \
        }

    // ---- layers ----
    #pragma unroll
    for (int l = 0; l < NL; ++l) {
        // CNOT ring (0,1)(1,2)(2,3)(3,4)(4,5)(5,0); qubit w <-> bit mask 32>>w
        CNOT(32, 16)
        CNOT(16,  8)
        CNOT( 8,  4)
        CNOT( 4,  2)
        CNOT( 2,  1)
        CNOT( 1, 32)

        // RY(q_w) for w=0..5: Givens rotation on pairs (i, i | (32>>w))
        #pragma unroll
        for (int w = 0; w < 6; ++w) {
            float st, ct;
            __sincosf(weights[l * 6 + w] * 0.5f, &st, &ct);
            v2f ctv; ctv.x = ct; ctv.y = ct;
            v2f stv; stv.x = st; stv.y = st;
            const int m = 32 >> w;
            #pragma unroll
            for (int i = 0; i < 64; ++i) {
                if (i & m) continue;
                const int j = i | m;
                const v2f a0 = a[i], a1 = a[j];
                a[i] = ctv * a0 - stv * a1;
                a[j] = stv * a0 + ctv * a1;
            }
        }
    }
    #undef CNOT

    // ---- <Z_w> w=0..3 ----
    // probabilities, reduced over ancillas (low 2 bits) first; keep re^2/im^2 in
    // the two v2f slots through the whole reduction, split only at the end.
    v2f s16[16];
    #pragma unroll
    for (int h = 0; h < 16; ++h) {
        const v2f p0 = a[4 * h + 0] * a[4 * h + 0];
        const v2f p1 = a[4 * h + 1] * a[4 * h + 1];
        const v2f p2 = a[4 * h + 2] * a[4 * h + 2];
        const v2f p3 = a[4 * h + 3] * a[4 * h + 3];
        s16[h] = (p0 + p1) + (p2 + p3);
    }
    // shared butterfly: z_w = sum_h sign(bit of h) * s16[h]
    // h bit3=q0, bit2=q1, bit1=q2, bit0=q3
    v2f u8[8], z3v; z3v.x = 0.f; z3v.y = 0.f;
    #pragma unroll
    for (int h = 0; h < 8; ++h) {
        u8[h] = s16[2 * h] + s16[2 * h + 1];
        z3v  += s16[2 * h] - s16[2 * h + 1];
    }
    v2f u4[4], z2v; z2v.x = 0.f; z2v.y = 0.f;
    #pragma unroll
    for (int h = 0; h < 4; ++h) {
        u4[h] = u8[2 * h] + u8[2 * h + 1];
        z2v  += u8[2 * h] - u8[2 * h + 1];
    }
    const v2f z1v = (u4[0] - u4[1]) + (u4[2] - u4[3]);
    const v2f z0v = (u4[0] + u4[1]) - (u4[2] + u4[3]);

    float4 o;
    o.x = z0v.x + z0v.y;
    o.y = z1v.x + z1v.y;
    o.z = z2v.x + z2v.y;
    o.w = z3v.x + z3v.y;
    *reinterpret_cast<float4*>(out + sample * 4) = o;  // 16B coalesced
}

extern "C" void kernel_launch(void* const* d_in, const int* in_sizes, int n_in,
                              void* d_out, int out_size, void* d_ws, size_t ws_size,
                              hipStream_t stream) {
    const float* x       = (const float*)d_in[0];  // (B, 4)
    const float* weights = (const float*)d_in[1];  // (2, 6)
    const float* bias    = (const float*)d_in[2];  // (2,)
    float* out = (float*)d_out;                    // (B, 4)
    const int B = in_sizes[0] / 4;
    qcirc6_reg_kernel<<<(B + 255) / 256, 256, 0, stream>>>(x, weights, bias, out, B);
}